// Round 1
// baseline (797.513 us; speedup 1.0000x reference)
//
#include <hip/hip_runtime.h>

// CfCHead: B=64, S=2048, H=1024 sequential scan.
// One thread per (b, j) chain; 256 blocks x 256 threads = 65536 threads
// (= 4 waves/CU on 256 CUs, the max TLP this problem admits).
// Per-step H-reduction for the 2-wide projection: wave shfl_xor reduce ->
// per-wave LDS slot (no intra-loop barrier) -> block fold -> atomicAdd.

#define Bv 64
#define Sv 2048
#define Hv 1024
#define TPB 256
#define BLK_PER_B (Hv / TPB)   // 4 blocks cover one batch row

__device__ __forceinline__ float fexp2(float x) { return __builtin_amdgcn_exp2f(x); }
__device__ __forceinline__ float frcp(float x)  { return __builtin_amdgcn_rcpf(x); }

#define L2E 1.44269504088896340736f

// out[b*S*2 + t*2 + k] = proj_b[k]  (also clears the 0xAA poison)
__global__ __launch_bounds__(256) void init_out(const float* __restrict__ proj_b,
                                                float* __restrict__ out) {
    int i = blockIdx.x * 256 + threadIdx.x;   // grid sized exactly to out_size
    out[i] = proj_b[i & 1];
}

__global__ __launch_bounds__(TPB) void cfc_scan(
    const float* __restrict__ x_codes,
    const float* __restrict__ Wi_w, const float* __restrict__ Wi_b,
    const float* __restrict__ Wf_w, const float* __restrict__ Wf_b,
    const float* __restrict__ Wo_w, const float* __restrict__ Wo_b,
    const float* __restrict__ Wg_w, const float* __restrict__ Wg_b,
    const float* __restrict__ Wl_w, const float* __restrict__ Wl_b,
    const float* __restrict__ proj_w,
    const float* __restrict__ n_init,
    float* __restrict__ out)
{
    // [t][wave][k] wave-level partial sums; 2048*4*2*4B = 64 KB exactly.
    __shared__ float part[Sv * 8];

    const int b    = blockIdx.x >> 2;        // batch row
    const int q    = blockIdx.x & 3;         // which quarter of H
    const int tid  = threadIdx.x;
    const int j    = q * TPB + tid;          // hidden index
    const int wave = tid >> 6;
    const int lane = tid & 63;

    // Per-chain constants (coalesced loads)
    const float wi = Wi_w[j], bi = Wi_b[j];
    const float wf = Wf_w[j], bf = Wf_b[j];
    const float wo = Wo_w[j], bo = Wo_b[j];
    const float wg = Wg_w[j], bg = Wg_b[j];
    const float wl = Wl_w[j], bl = Wl_b[j];
    const float pw0 = proj_w[j], pw1 = proj_w[Hv + j];

    float n = n_init[j];
    float h = 0.0f, c = 0.0f;

    const float* __restrict__ xrow = x_codes + b * Sv;  // uniform in block -> s_load

    #pragma unroll 4
    for (int t = 0; t < Sv; ++t) {
        const float xt = fmaf(xrow[t], 0.01f, -0.65f);   // (code-65)/100
        // 5 independent gate pre-activations
        const float pi = fmaf(xt, wi, bi);
        const float pf = fmaf(xt, wf, bf);
        const float po = fmaf(xt, wo, bo);
        const float pg = fmaf(xt, wg, bg);
        const float pl = fmaf(xt, wl, bl);
        // 5 independent transcendentals (ILP to hide v_exp latency)
        const float ei = fexp2((pi - n) * L2E);
        const float ef = fexp2((pf - n) * L2E);
        const float eo = fexp2((po - n) * L2E);
        const float g   = frcp(1.0f + fexp2(pg * -L2E));  // sigmoid(pg)
        const float lam = frcp(1.0f + fexp2(pl * -L2E));  // sigmoid(pl)

        c = fmaf(ef, c, ei * g);
        const float sc = frcp(1.0f + fexp2(c * -L2E));    // sigmoid(c)
        const float ff = eo * sc;
        h = (h + 0.01f * ff) * frcp(fmaf(0.01f, lam, 1.0f));
        n = fmaf(0.01f, (ei + ef + eo) - 3.0f, n);

        // Projection contribution of this lane; reduce across the wave.
        float p0 = h * pw0;
        float p1 = h * pw1;
        #pragma unroll
        for (int m = 32; m; m >>= 1) {
            p0 += __shfl_xor(p0, m, 64);
            p1 += __shfl_xor(p1, m, 64);
        }
        // Result only feeds an LDS store in a per-wave slot: no barrier needed,
        // shuffle chain of step t overlaps compute of step t+1.
        if (lane == 0) {
            part[t * 8 + wave * 2 + 0] = p0;
            part[t * 8 + wave * 2 + 1] = p1;
        }
    }

    __syncthreads();

    // Fold the 4 wave partials and accumulate into the global output.
    float* __restrict__ orow = out + b * (Sv * 2);
    for (int idx = tid; idx < Sv * 2; idx += TPB) {
        const int t = idx >> 1;
        const int k = idx & 1;
        const float v = part[t * 8 + 0 + k] + part[t * 8 + 2 + k] +
                        part[t * 8 + 4 + k] + part[t * 8 + 6 + k];
        atomicAdd(&orow[idx], v);
    }
}

extern "C" void kernel_launch(void* const* d_in, const int* in_sizes, int n_in,
                              void* d_out, int out_size, void* d_ws, size_t ws_size,
                              hipStream_t stream) {
    const float* x_codes = (const float*)d_in[0];
    const float* Wi_w = (const float*)d_in[1];
    const float* Wi_b = (const float*)d_in[2];
    const float* Wf_w = (const float*)d_in[3];
    const float* Wf_b = (const float*)d_in[4];
    const float* Wo_w = (const float*)d_in[5];
    const float* Wo_b = (const float*)d_in[6];
    const float* Wg_w = (const float*)d_in[7];
    const float* Wg_b = (const float*)d_in[8];
    const float* Wl_w = (const float*)d_in[9];
    const float* Wl_b = (const float*)d_in[10];
    const float* proj_w = (const float*)d_in[11];
    const float* proj_b = (const float*)d_in[12];
    const float* n_init = (const float*)d_in[13];
    float* out = (float*)d_out;

    // out_size = B*S*2 = 262144 -> 1024 blocks of 256
    init_out<<<out_size / 256, 256, 0, stream>>>(proj_b, out);
    cfc_scan<<<Bv * BLK_PER_B, TPB, 0, stream>>>(
        x_codes, Wi_w, Wi_b, Wf_w, Wf_b, Wo_w, Wo_b, Wg_w, Wg_b, Wl_w, Wl_b,
        proj_w, n_init, out);
}

// Round 2
// 359.461 us; speedup vs baseline: 2.2186x; 2.2186x over previous
//
#include <hip/hip_runtime.h>

// CfCHead: B=64, S=2048, H=1024 sequential nonlinear scan.
// One thread per (b,j) chain; 256 blocks x 256 threads = 1024 waves = exactly
// 1 wave/SIMD on 256 CUs -> ALL latency hiding must come from ILP.
//
// Round-2 structure (vs round-1's per-step shuffle reduce, 880 cyc/step):
//  - chunk of 16 steps: precompute all x-only transcendentals (5/step) with
//    full ILP, leaving only En=exp2(-n*L2E) and sigmoid(c) on the serial chain
//  - n's deterministic -0.03/step drift folded into precomputed gate
//    exponents (+0.0433*u), rebased once per chunk -> shortest n-chain
//  - h buffered 16 steps in regs, one LDS-transpose reduce per chunk
//    (stride-17 rows: conflict-free writes, ~2-way reads), 3 shfl + atomicAdd

#define Bv 64
#define Sv 2048
#define Hv 1024
#define TPB 256
#define CH 16

#define L2E   1.44269504088896340736f
#define NL2E (-1.44269504088896340736f)
#define LN2   0.69314718055994530942f
#define KNU   0.014426950408889634f     /* 0.01*L2E  */
#define CU1   0.043280851226668902f     /* 0.03*L2E  */
#define CREB  0.692493619626702435f     /* 16*0.03*L2E */

__device__ __forceinline__ float fexp2(float x) { return __builtin_amdgcn_exp2f(x); }
__device__ __forceinline__ float frcp(float x)  { return __builtin_amdgcn_rcpf(x); }

// out[b*S*2 + t*2 + k] = proj_b[k]  (clears 0xAA poison; scan atomically adds)
__global__ __launch_bounds__(256) void init_out(const float* __restrict__ proj_b,
                                                float* __restrict__ out) {
    int i = blockIdx.x * 256 + threadIdx.x;
    out[i] = proj_b[i & 1];
}

__global__ __launch_bounds__(TPB, 1) void cfc_scan(
    const float* __restrict__ x_codes,
    const float* __restrict__ Wi_w, const float* __restrict__ Wi_b,
    const float* __restrict__ Wf_w, const float* __restrict__ Wf_b,
    const float* __restrict__ Wo_w, const float* __restrict__ Wo_b,
    const float* __restrict__ Wg_w, const float* __restrict__ Wg_b,
    const float* __restrict__ Wl_w, const float* __restrict__ Wl_b,
    const float* __restrict__ proj_w,
    const float* __restrict__ n_init,
    float* __restrict__ out)
{
    // transpose buffers: row j (=tid) holds 16 chunk-local h*pw values.
    // stride 17 floats: writes conflict-free (17 odd), reads ~2-way.
    __shared__ float v0[TPB * 17];
    __shared__ float v1[TPB * 17];

    const int b   = blockIdx.x >> 2;
    const int q   = blockIdx.x & 3;
    const int tid = threadIdx.x;
    const int j   = q * TPB + tid;

    const float wi = Wi_w[j], bi = Wi_b[j];
    const float wf = Wf_w[j], bf = Wf_b[j];
    const float wo = Wo_w[j], bo = Wo_b[j];
    const float wg = Wg_w[j], bg = Wg_b[j];
    const float wl = Wl_w[j], bl = Wl_b[j];
    const float pw0 = proj_w[j], pw1 = proj_w[Hv + j];

    // m = -n * L2E  (so En = exp2(m) = e^{-n});  C = -c * L2E
    float m  = n_init[j] * NL2E;
    float En = fexp2(m);
    float h = 0.0f, C = 0.0f;

    const float* __restrict__ xrow = x_codes + b * Sv;
    float* __restrict__ orow = out + b * (Sv * 2);

    // reduce-phase thread mapping: k = tid>>7, t_local = (tid>>3)&15, seg = tid&7
    const int rk   = tid >> 7;
    const int rt   = (tid >> 3) & 15;
    const int rseg = tid & 7;
    const float* __restrict__ rbase = rk ? v1 : v0;

    float Gi[CH], Gf[CH], Go[CH], Gg[CH], Il[CH], hb[CH];

    for (int t0 = 0; t0 < Sv; t0 += CH) {
        // ---- precompute: x-only transcendentals, fully independent (ILP) ----
        #pragma unroll
        for (int u = 0; u < CH; ++u) {
            const float Cu = CU1 * (float)u;        // folds n's -0.03/step drift
            const float xt = fmaf(xrow[t0 + u], 0.01f, -0.65f);
            Gi[u] = fexp2(fmaf(fmaf(xt, wi, bi), L2E, Cu));   // e^{pre_i} * 2^{Cu}
            Gf[u] = fexp2(fmaf(fmaf(xt, wf, bf), L2E, Cu));
            Go[u] = fexp2(fmaf(fmaf(xt, wo, bo), L2E, Cu));
            const float eg = fexp2(fmaf(xt, wg, bg) * NL2E);
            Gg[u] = frcp(fmaf(eg, -LN2, -LN2));               // = -L2E * sigmoid(pre_g)
            const float el = fexp2(fmaf(xt, wl, bl) * NL2E);
            Il[u] = fmaf(-0.01f, frcp(el + 1.01f), 1.0f);     // 1/(1+0.01*sigmoid(pre_l))
        }

        // ---- recurrence: only En and sigmoid(c) are state-dependent trans ----
        #pragma unroll
        for (int u = 0; u < CH; ++u) {
            const float ei = Gi[u] * En;
            const float ef = Gf[u] * En;
            const float eo = Go[u] * En;
            C = fmaf(ef, C, ei * Gg[u]);                 // C = -L2E * c_new
            const float sc = frcp(1.0f + fexp2(C));      // sigmoid(c_new)
            h = fmaf(0.01f * eo, sc, h) * Il[u];
            hb[u] = h;
            m = fmaf(-KNU, (ei + ef) + eo, m);
            if (u == CH - 1) m += CREB;                  // rebase drift once/chunk
            En = fexp2(m);
        }

        // ---- batched projection reduce ----
        #pragma unroll
        for (int u = 0; u < CH; ++u) {
            v0[tid * 17 + u] = hb[u] * pw0;
            v1[tid * 17 + u] = hb[u] * pw1;
        }
        __syncthreads();

        float sum = 0.0f;
        #pragma unroll
        for (int i2 = 0; i2 < 32; ++i2) {
            const int jj = rseg * 32 + ((i2 + 8 * rseg) & 31);  // rotation: 2-way banks
            sum += rbase[jj * 17 + rt];
        }
        sum += __shfl_xor(sum, 1, 64);
        sum += __shfl_xor(sum, 2, 64);
        sum += __shfl_xor(sum, 4, 64);
        if (rseg == 0) atomicAdd(&orow[(t0 + rt) * 2 + rk], sum);
        __syncthreads();
    }
}

extern "C" void kernel_launch(void* const* d_in, const int* in_sizes, int n_in,
                              void* d_out, int out_size, void* d_ws, size_t ws_size,
                              hipStream_t stream) {
    const float* x_codes = (const float*)d_in[0];
    const float* Wi_w = (const float*)d_in[1];
    const float* Wi_b = (const float*)d_in[2];
    const float* Wf_w = (const float*)d_in[3];
    const float* Wf_b = (const float*)d_in[4];
    const float* Wo_w = (const float*)d_in[5];
    const float* Wo_b = (const float*)d_in[6];
    const float* Wg_w = (const float*)d_in[7];
    const float* Wg_b = (const float*)d_in[8];
    const float* Wl_w = (const float*)d_in[9];
    const float* Wl_b = (const float*)d_in[10];
    const float* proj_w = (const float*)d_in[11];
    const float* proj_b = (const float*)d_in[12];
    const float* n_init = (const float*)d_in[13];
    float* out = (float*)d_out;

    init_out<<<out_size / 256, 256, 0, stream>>>(proj_b, out);
    cfc_scan<<<Bv * (Hv / TPB), TPB, 0, stream>>>(
        x_codes, Wi_w, Wi_b, Wf_w, Wf_b, Wo_w, Wo_b, Wg_w, Wg_b, Wl_w, Wl_b,
        proj_w, n_init, out);
}

// Round 3
// 261.229 us; speedup vs baseline: 3.0529x; 1.3760x over previous
//
#include <hip/hip_runtime.h>

// CfCHead: B=64, S=2048, H=1024 sequential nonlinear scan.
// Round-3: producer/consumer wave split + log2-domain algebra.
//  - 256 blocks x 512 threads: waves 0-3 run 256 chains (j quarter), waves
//    4-7 reduce the projection. ONE barrier/chunk, double-buffered h in LDS.
//  - all affine transforms folded into per-thread weights (code -> exponent
//    is a single fma); 0.01*o_t folded via log2(0.01); n's deterministic
//    -0.03/step drift folded into per-u literal 2^{0.03u}, rebased per chunk.
//  - recurrence per step: 10 VALU + 3 trans; m-chain = exp2 -> mul -> fmac.

#define Bv   64
#define Sv   2048
#define Hv   1024
#define TPB  256      // producer (chain) threads per block
#define NT   512      // total threads per block
#define CH   16       // chunk (time steps per barrier)
#define HSTR 17       // LDS row stride (floats), odd -> conflict-free
#define HBUF (TPB * HSTR)

#define L2E   1.44269504088896340736f
#define NL2E (-1.44269504088896340736f)
#define LN2   0.69314718055994530942f
#define KNU   0.014426950408889634f     /* 0.01*L2E          */
#define CREB  0.692493619626702435f     /* 16*0.03*L2E       */
#define LOG2_001 (-6.6438561897747247f) /* log2(0.01)        */

__device__ __forceinline__ float fexp2(float x) { return __builtin_amdgcn_exp2f(x); }
__device__ __forceinline__ float frcp(float x)  { return __builtin_amdgcn_rcpf(x); }

// out[b*S*2 + t*2 + k] = proj_b[k]  (clears 0xAA poison; scan atomically adds)
__global__ __launch_bounds__(256) void init_out(const float* __restrict__ proj_b,
                                                float* __restrict__ out) {
    int i = blockIdx.x * 256 + threadIdx.x;
    out[i] = proj_b[i & 1];
}

__global__ __launch_bounds__(NT, 1) void cfc_scan(
    const float* __restrict__ x_codes,
    const float* __restrict__ Wi_w, const float* __restrict__ Wi_b,
    const float* __restrict__ Wf_w, const float* __restrict__ Wf_b,
    const float* __restrict__ Wo_w, const float* __restrict__ Wo_b,
    const float* __restrict__ Wg_w, const float* __restrict__ Wg_b,
    const float* __restrict__ Wl_w, const float* __restrict__ Wl_b,
    const float* __restrict__ proj_w,
    const float* __restrict__ n_init,
    float* __restrict__ out)
{
    __shared__ float hlds[2 * HBUF];    // double-buffered raw h, [par][j][u]
    __shared__ float pwlds[2 * TPB];    // proj_w staged, [k][j_local]

    const int b   = blockIdx.x >> 2;
    const int q   = blockIdx.x & 3;
    const int tid = threadIdx.x;

    const float* __restrict__ xrow = x_codes + b * Sv;
    float* __restrict__ orow = out + b * (Sv * 2);

    // ---- consumer setup (waves 4-7) ----
    const int ct   = tid - TPB;
    const int rk   = (ct >> 7) & 1;
    const int rt   = (ct >> 3) & 15;
    const int rseg = ct & 7;
    if (tid >= TPB) {
        pwlds[ct]       = proj_w[q * TPB + ct];
        pwlds[TPB + ct] = proj_w[Hv + q * TPB + ct];
    }

    // ---- producer setup (waves 0-3): fold all affine maps into weights ----
    float wi2 = 0, bi2 = 0, wf2 = 0, bf2 = 0, wo2 = 0, bo2 = 0;
    float wg2 = 0, bg2 = 0, wl2 = 0, bl2 = 0;
    float m = 0, En = 0, C = 0, h = 0;
    if (tid < TPB) {
        const int j = q * TPB + tid;
        const float wi = Wi_w[j], bi = Wi_b[j];
        const float wf = Wf_w[j], bf = Wf_b[j];
        const float wo = Wo_w[j], bo = Wo_b[j];
        const float wg = Wg_w[j], bg = Wg_b[j];
        const float wl = Wl_w[j], bl = Wl_b[j];
        // pre = ((code-65)/100)*w + b ; exponent_arg = pre*L2E = code*w' + b'
        wi2 = wi * KNU;  bi2 = fmaf(-0.65f, wi, bi) * L2E;
        wf2 = wf * KNU;  bf2 = fmaf(-0.65f, wf, bf) * L2E;
        wo2 = wo * KNU;  bo2 = fmaf(-0.65f, wo, bo) * L2E + LOG2_001; // 0.01*e^pre_o
        wg2 = -wg * KNU; bg2 = fmaf(-0.65f, wg, bg) * NL2E;           // for e^{-pre_g}
        wl2 = -wl * KNU; bl2 = fmaf(-0.65f, wl, bl) * NL2E;
        m  = n_init[j] * NL2E;   // m = -n*L2E (drift-free form)
        En = fexp2(m);           // e^{-n}
    }

    float Gf[CH], GiGg[CH], Goa[CH], Gs[CH], Il[CH];

    // 2^{0.03*L2E*u} = e^{0.03u}: per-step drift of e^{-n}, compile-time
    static const float CUP[CH] = {
        1.0f,        1.03045453f, 1.06183655f, 1.09417428f,
        1.12749685f, 1.16183424f, 1.19721736f, 1.23367806f,
        1.27124915f, 1.30996445f, 1.34985881f, 1.39096813f,
        1.43332941f, 1.47698079f, 1.52196156f, 1.56831219f };

    int par = 0;
    for (int t0 = 0; t0 < Sv; t0 += CH, par ^= 1) {
        if (tid < TPB) {
            // -- x-only transcendentals, fully independent (ILP) --
            #pragma unroll
            for (int u = 0; u < CH; ++u) {
                const float xc = xrow[t0 + u];
                const float Gi = fexp2(fmaf(xc, wi2, bi2));   // e^{pre_i}
                Gf[u]  = fexp2(fmaf(xc, wf2, bf2));           // e^{pre_f}
                Goa[u] = fexp2(fmaf(xc, wo2, bo2));           // 0.01*e^{pre_o}
                const float eg = fexp2(fmaf(xc, wg2, bg2));   // e^{-pre_g}
                const float Gg = frcp(fmaf(eg, -LN2, -LN2));  // -L2E*sigmoid(pre_g)
                GiGg[u] = Gi * Gg;
                const float el = fexp2(fmaf(xc, wl2, bl2));   // e^{-pre_l}
                Il[u]   = fmaf(frcp(el + 1.01f), -0.01f, 1.0f); // 1/(1+.01*sig)
                Gs[u]   = fmaf(Goa[u], 100.0f, Gi + Gf[u]);   // e^pi+e^pf+e^po
            }
            // -- serial recurrence: chain = exp2 -> mul -> fmac --
            float* __restrict__ hrow = &hlds[par * HBUF + tid * HSTR];
            #pragma unroll
            for (int u = 0; u < CH; ++u) {
                const float Enu = (u == 0) ? En : En * CUP[u];  // e^{-n_t}
                const float ef  = Gf[u] * Enu;                  // f_t
                C = fmaf(ef, C, GiGg[u] * Enu);                 // C = -L2E*c
                const float sc = frcp(1.0f + fexp2(C));         // sigmoid(c)
                h = fmaf(Goa[u] * Enu, sc, h) * Il[u];
                hrow[u] = h;
                m = fmaf(Gs[u] * Enu, -KNU, m);
                if (u == CH - 1) m += CREB;                     // drift rebase
                En = fexp2(m);
            }
        }
        __syncthreads();   // producers publish h[par]; consumers sync to it
        if (tid >= TPB) {
            const float* __restrict__ hb  = &hlds[par * HBUF];
            const float* __restrict__ pwk = &pwlds[rk * TPB];
            float sum = 0.0f;
            #pragma unroll
            for (int i2 = 0; i2 < 32; ++i2) {
                const int v  = (i2 + 4 * rseg) & 31;   // rotation: 2-way banks
                const int jj = rseg * 32 + v;
                sum = fmaf(hb[jj * HSTR + rt], pwk[jj], sum);  // pw read = broadcast
            }
            sum += __shfl_xor(sum, 1, 64);
            sum += __shfl_xor(sum, 2, 64);
            sum += __shfl_xor(sum, 4, 64);
            if (rseg == 0) atomicAdd(&orow[(t0 + rt) * 2 + rk], sum);
        }
    }
}

extern "C" void kernel_launch(void* const* d_in, const int* in_sizes, int n_in,
                              void* d_out, int out_size, void* d_ws, size_t ws_size,
                              hipStream_t stream) {
    const float* x_codes = (const float*)d_in[0];
    const float* Wi_w = (const float*)d_in[1];
    const float* Wi_b = (const float*)d_in[2];
    const float* Wf_w = (const float*)d_in[3];
    const float* Wf_b = (const float*)d_in[4];
    const float* Wo_w = (const float*)d_in[5];
    const float* Wo_b = (const float*)d_in[6];
    const float* Wg_w = (const float*)d_in[7];
    const float* Wg_b = (const float*)d_in[8];
    const float* Wl_w = (const float*)d_in[9];
    const float* Wl_b = (const float*)d_in[10];
    const float* proj_w = (const float*)d_in[11];
    const float* proj_b = (const float*)d_in[12];
    const float* n_init = (const float*)d_in[13];
    float* out = (float*)d_out;

    init_out<<<out_size / 256, 256, 0, stream>>>(proj_b, out);
    cfc_scan<<<Bv * (Hv / TPB), NT, 0, stream>>>(
        x_codes, Wi_w, Wi_b, Wf_w, Wf_b, Wo_w, Wo_b, Wg_w, Wg_b, Wl_w, Wl_b,
        proj_w, n_init, out);
}